// Round 12
// baseline (671.654 us; speedup 1.0000x reference)
//
#include <hip/hip_runtime.h>
#include <math.h>

#define N_NODES 50000
#define N_EDGES 800000
#define BUCKET 64
#define NBLK 512
// F_IN = HID = 128, C = 40

typedef __attribute__((ext_vector_type(8))) short short8;
typedef __attribute__((ext_vector_type(4))) float f32x4;

__device__ __forceinline__ ushort f2bf(float f) {
    union { float f; uint u; } v; v.f = f;
    uint r = v.u + 0x7FFFu + ((v.u >> 16) & 1u);  // RNE
    return (ushort)(r >> 16);
}
__device__ __forceinline__ float bflo(uint p) {
    union { uint u; float f; } v; v.u = p << 16; return v.f;
}
__device__ __forceinline__ float bfhi(uint p) {
    union { uint u; float f; } v; v.u = p & 0xFFFF0000u; return v.f;
}

// 3-level cumulative grid barrier (64 shards -> 8 supers -> master -> gen).
// bar: shard[s*32] s<64 | super at 2048+u*32 u<8 | master at 2304 | gen at 2336. All zeroed pre-launch.
__device__ __forceinline__ void gsync(int* bar, int phase) {
    __syncthreads();
    if (threadIdx.x == 0) {
        __threadfence();
        const int s = blockIdx.x & 63;
        if (atomicAdd(&bar[s * 32], 1) == (phase + 1) * (NBLK / 64) - 1) {
            const int u = s & 7;
            if (atomicAdd(&bar[2048 + u * 32], 1) == (phase + 1) * 8 - 1) {
                if (atomicAdd(&bar[2304], 1) == (phase + 1) * 8 - 1) {
                    __threadfence();
                    atomicAdd(&bar[2336], 1);
                }
            }
        }
        while (__hip_atomic_load(&bar[2336], __ATOMIC_ACQUIRE, __HIP_MEMORY_SCOPE_AGENT) <= phase)
            __builtin_amdgcn_s_sleep(8);
        __threadfence();
    }
    __syncthreads();
}

__global__ __launch_bounds__(512, 4) void gcn_persistent_k(
        const float* __restrict__ x,
        const float* __restrict__ W1, const float* __restrict__ b1,
        const float* __restrict__ W2, const float* __restrict__ b2,
        const float* __restrict__ W3, const float* __restrict__ b3,
        const int* __restrict__ src, const int* __restrict__ dst,
        int* __restrict__ bar, int* __restrict__ cnt, ushort* __restrict__ colb,
        ushort* __restrict__ B0, ushort* __restrict__ B1, float* __restrict__ out) {
    __shared__ ushort sB[16384];  // 32KB: W fragments for gemm phases
    const int tid = threadIdx.x;
    const int bb = blockIdx.x;
    const int wid = tid >> 6, lane = tid & 63;
    const int lp = (lane & 56) | ((lane + (lane >> 3)) & 7);

    // ================= P1: scatter (blocks 0..255) | gemm1 (blocks 256..511) =================
    if (bb < 256) {
        const int r = bb & 7;              // dst range (aligned with de-facto XCD = bid%8)
        const int g = bb >> 3;             // chunk group 0..31
        const int lo = r * 6250;
        const int4* s32 = reinterpret_cast<const int4*>(src);
        const int4* d32 = reinterpret_cast<const int4*>(dst);
        const int qend = (g + 1) * 6250;   // 32 * 6250 = 200000 quads exactly
        for (int q = g * 6250 + tid; q < qend; q += 512) {
            const int4 d4 = d32[q];
            const int4 s4 = s32[q];
            if ((uint)(d4.x - lo) < 6250u) {
                int p = atomicAdd(&cnt[d4.x], 1);
                colb[(size_t)d4.x * BUCKET + p] = (ushort)s4.x;
            }
            if ((uint)(d4.y - lo) < 6250u) {
                int p = atomicAdd(&cnt[d4.y], 1);
                colb[(size_t)d4.y * BUCKET + p] = (ushort)s4.y;
            }
            if ((uint)(d4.z - lo) < 6250u) {
                int p = atomicAdd(&cnt[d4.z], 1);
                colb[(size_t)d4.z * BUCKET + p] = (ushort)s4.z;
            }
            if ((uint)(d4.w - lo) < 6250u) {
                int p = atomicAdd(&cnt[d4.w], 1);
                colb[(size_t)d4.w * BUCKET + p] = (ushort)s4.w;
            }
        }
    } else {
        // ---- gemm1: B1 = cvt(x) @ W1 (raw rows), 2 tiles/wave ----
        for (int i = tid; i < 128 * 128; i += 512) {
            const int k = i >> 7, n = i & 127;
            const int s = k >> 5, r2 = (k >> 3) & 3, j = k & 7;
            const int t = n >> 4, nl = n & 15;
            const int l = r2 * 16 + nl;
            const int lw = (l & 56) | ((l + (l >> 3)) & 7);
            sB[(((s * 8 + t) * 64) + lw) * 8 + j] = f2bf(W1[k * 128 + n]);
        }
        __syncthreads();
        const int bb2 = bb - 256;
        const int t0 = bb2 * 16 + wid * 2, t1 = t0 + 1;
        const int t0c = min(t0, 3124), t1c = min(t1, 3124);
        f32x4 acc[2][8];
#pragma unroll
        for (int u = 0; u < 2; u++)
#pragma unroll
            for (int t = 0; t < 8; t++) acc[u][t] = (f32x4){0.f, 0.f, 0.f, 0.f};
#pragma unroll
        for (int s = 0; s < 4; s++) {
            short8 a0, a1;
            const int ko = 32 * s + 8 * (lane >> 4);
            const float4* p0 = reinterpret_cast<const float4*>(x + (size_t)(t0c * 16 + (lane & 15)) * 128 + ko);
            const float4* p1 = reinterpret_cast<const float4*>(x + (size_t)(t1c * 16 + (lane & 15)) * 128 + ko);
            float4 u0 = p0[0], u1 = p0[1], v0 = p1[0], v1 = p1[1];
            a0[0] = f2bf(u0.x); a0[1] = f2bf(u0.y); a0[2] = f2bf(u0.z); a0[3] = f2bf(u0.w);
            a0[4] = f2bf(u1.x); a0[5] = f2bf(u1.y); a0[6] = f2bf(u1.z); a0[7] = f2bf(u1.w);
            a1[0] = f2bf(v0.x); a1[1] = f2bf(v0.y); a1[2] = f2bf(v0.z); a1[3] = f2bf(v0.w);
            a1[4] = f2bf(v1.x); a1[5] = f2bf(v1.y); a1[6] = f2bf(v1.z); a1[7] = f2bf(v1.w);
#pragma unroll
            for (int t = 0; t < 8; t++) {
                short8 b = *reinterpret_cast<const short8*>(&sB[(((s * 8 + t) * 64) + lp) * 8]);
                acc[0][t] = __builtin_amdgcn_mfma_f32_16x16x32_bf16(a0, b, acc[0][t], 0, 0, 0);
                acc[1][t] = __builtin_amdgcn_mfma_f32_16x16x32_bf16(a1, b, acc[1][t], 0, 0, 0);
            }
        }
        const int rl = 4 * (lane >> 4), cl = lane & 15;
#pragma unroll
        for (int u = 0; u < 2; u++) {
            const int tile = u ? t1 : t0;
            if (tile >= 3125) continue;
            const int row0 = tile * 16;
#pragma unroll
            for (int t = 0; t < 8; t++) {
                const int c = 16 * t + cl;
#pragma unroll
                for (int g = 0; g < 4; g++)
                    B1[(size_t)(row0 + rl + g) * 128 + c] = f2bf(acc[u][t][g]);
            }
        }
    }
    gsync(bar, 0);

    // ================= P2: gather1 — h1 = relu(Ahat @ XW1 + b1) -> B0 =================
    {
        const uint* XW32 = reinterpret_cast<const uint*>(B1);
        for (int node = bb * 8 + wid; node < N_NODES; node += NBLK * 8) {
            const int n = cnt[node];
            const float di = rsqrtf((float)(n + 1));
            int sl = 0; float wl = 0.f;
            if (lane < n) {
                sl = colb[(size_t)node * BUCKET + lane];
                wl = rsqrtf((float)(cnt[sl] + 1));
            }
            float a0 = 0.f, a1 = 0.f, b0 = 0.f, b1v = 0.f;
            float c0 = 0.f, c1 = 0.f, d0 = 0.f, d1 = 0.f;
            int e = 0;
            for (; e + 4 <= n; e += 4) {
                const int s0 = __shfl(sl, e),     s1 = __shfl(sl, e + 1);
                const int s2 = __shfl(sl, e + 2), s3 = __shfl(sl, e + 3);
                const float w0 = __shfl(wl, e),     w1 = __shfl(wl, e + 1);
                const float w2 = __shfl(wl, e + 2), w3 = __shfl(wl, e + 3);
                const uint p0 = XW32[(size_t)s0 * 64 + lane];
                const uint p1 = XW32[(size_t)s1 * 64 + lane];
                const uint p2 = XW32[(size_t)s2 * 64 + lane];
                const uint p3 = XW32[(size_t)s3 * 64 + lane];
                a0 = fmaf(bflo(p0), w0, a0); a1 = fmaf(bfhi(p0), w0, a1);
                b0 = fmaf(bflo(p1), w1, b0); b1v = fmaf(bfhi(p1), w1, b1v);
                c0 = fmaf(bflo(p2), w2, c0); c1 = fmaf(bfhi(p2), w2, c1);
                d0 = fmaf(bflo(p3), w3, d0); d1 = fmaf(bfhi(p3), w3, d1);
            }
            for (; e < n; e++) {
                const int s = __shfl(sl, e);
                const float w = __shfl(wl, e);
                const uint p = XW32[(size_t)s * 64 + lane];
                a0 = fmaf(bflo(p), w, a0); a1 = fmaf(bfhi(p), w, a1);
            }
            const uint ps = XW32[(size_t)node * 64 + lane];
            float t0 = (a0 + b0) + (c0 + d0); t0 = fmaf(bflo(ps), di, t0);
            float t1 = (a1 + b1v) + (c1 + d1); t1 = fmaf(bfhi(ps), di, t1);
            const float o0 = fmaxf(fmaf(di, t0, b1[2 * lane]), 0.f);
            const float o1 = fmaxf(fmaf(di, t1, b1[2 * lane + 1]), 0.f);
            reinterpret_cast<uint*>(B0)[(size_t)node * 64 + lane] =
                (uint)f2bf(o0) | ((uint)f2bf(o1) << 16);
        }
    }
    gsync(bar, 1);

    // ================= P3: gemm2 — B1 = (B0 @ W2) * dinv[row], 1 tile/wave =================
    {
        for (int i = tid; i < 128 * 128; i += 512) {
            const int k = i >> 7, n = i & 127;
            const int s = k >> 5, r2 = (k >> 3) & 3, j = k & 7;
            const int t = n >> 4, nl = n & 15;
            const int l = r2 * 16 + nl;
            const int lw = (l & 56) | ((l + (l >> 3)) & 7);
            sB[(((s * 8 + t) * 64) + lw) * 8 + j] = f2bf(W2[k * 128 + n]);
        }
        __syncthreads();
        const int t = bb * 8 + wid;
        if (t < 3125) {
            const int row0 = t * 16;
            f32x4 acc[8];
#pragma unroll
            for (int q = 0; q < 8; q++) acc[q] = (f32x4){0.f, 0.f, 0.f, 0.f};
#pragma unroll
            for (int s = 0; s < 4; s++) {
                const int ko = 32 * s + 8 * (lane >> 4);
                short8 a = *reinterpret_cast<const short8*>(B0 + (size_t)(row0 + (lane & 15)) * 128 + ko);
#pragma unroll
                for (int q = 0; q < 8; q++) {
                    short8 b = *reinterpret_cast<const short8*>(&sB[(((s * 8 + q) * 64) + lp) * 8]);
                    acc[q] = __builtin_amdgcn_mfma_f32_16x16x32_bf16(a, b, acc[q], 0, 0, 0);
                }
            }
            const int rl = 4 * (lane >> 4), cl = lane & 15;
#pragma unroll
            for (int g = 0; g < 4; g++) {
                const int row = row0 + rl + g;
                const float dr = rsqrtf((float)(cnt[row] + 1));
#pragma unroll
                for (int q = 0; q < 8; q++)
                    B1[(size_t)row * 128 + 16 * q + cl] = f2bf(acc[q][g] * dr);
            }
        }
    }
    gsync(bar, 2);

    // ================= P4: gather_add — h2 = relu(di*(sum B1 + self) + b2) -> B0 =================
    {
        const uint* XW32 = reinterpret_cast<const uint*>(B1);
        for (int node = bb * 8 + wid; node < N_NODES; node += NBLK * 8) {
            const int n = cnt[node];
            const float di = rsqrtf((float)(n + 1));
            const ushort4* bucket = reinterpret_cast<const ushort4*>(colb + (size_t)node * BUCKET);
            float a0 = 0.f, a1 = 0.f, b0 = 0.f, b1v = 0.f;
            float c0 = 0.f, c1 = 0.f, d0 = 0.f, d1 = 0.f;
            int e = 0;
            for (; e + 4 <= n; e += 4) {
                const ushort4 s4 = bucket[e >> 2];
                const uint p0 = XW32[(size_t)s4.x * 64 + lane];
                const uint p1 = XW32[(size_t)s4.y * 64 + lane];
                const uint p2 = XW32[(size_t)s4.z * 64 + lane];
                const uint p3 = XW32[(size_t)s4.w * 64 + lane];
                a0 += bflo(p0); a1 += bfhi(p0);
                b0 += bflo(p1); b1v += bfhi(p1);
                c0 += bflo(p2); c1 += bfhi(p2);
                d0 += bflo(p3); d1 += bfhi(p3);
            }
            for (; e < n; e++) {
                const ushort s = colb[(size_t)node * BUCKET + e];
                const uint p = XW32[(size_t)s * 64 + lane];
                a0 += bflo(p); a1 += bfhi(p);
            }
            const uint ps = XW32[(size_t)node * 64 + lane];
            const float t0 = ((a0 + b0) + (c0 + d0)) + bflo(ps);
            const float t1 = ((a1 + b1v) + (c1 + d1)) + bfhi(ps);
            const float o0 = fmaxf(fmaf(di, t0, b2[2 * lane]), 0.f);
            const float o1 = fmaxf(fmaf(di, t1, b2[2 * lane + 1]), 0.f);
            reinterpret_cast<uint*>(B0)[(size_t)node * 64 + lane] =
                (uint)f2bf(o0) | ((uint)f2bf(o1) << 16);
        }
    }
    gsync(bar, 3);

    // ================= P5: gemm3 — B1(40-wide) = (B0 @ W3) * dinv[row], 1 tile/wave =================
    {
        for (int i = tid; i < 128 * 48; i += 512) {
            const int k = i / 48, n = i % 48;
            const int s = k >> 5, r2 = (k >> 3) & 3, j = k & 7;
            const int t = n >> 4, nl = n & 15;
            const int l = r2 * 16 + nl;
            const int lw = (l & 56) | ((l + (l >> 3)) & 7);
            sB[(((s * 3 + t) * 64) + lw) * 8 + j] = (n < 40) ? f2bf(W3[k * 40 + n]) : (ushort)0;
        }
        __syncthreads();
        const int t = bb * 8 + wid;
        if (t < 3125) {
            const int row0 = t * 16;
            f32x4 acc[3];
#pragma unroll
            for (int q = 0; q < 3; q++) acc[q] = (f32x4){0.f, 0.f, 0.f, 0.f};
#pragma unroll
            for (int s = 0; s < 4; s++) {
                const int ko = 32 * s + 8 * (lane >> 4);
                short8 a = *reinterpret_cast<const short8*>(B0 + (size_t)(row0 + (lane & 15)) * 128 + ko);
#pragma unroll
                for (int q = 0; q < 3; q++) {
                    short8 b = *reinterpret_cast<const short8*>(&sB[(((s * 3 + q) * 64) + lp) * 8]);
                    acc[q] = __builtin_amdgcn_mfma_f32_16x16x32_bf16(a, b, acc[q], 0, 0, 0);
                }
            }
            const int rl = 4 * (lane >> 4), cl = lane & 15;
#pragma unroll
            for (int g = 0; g < 4; g++) {
                const int row = row0 + rl + g;
                const float dr = rsqrtf((float)(cnt[row] + 1));
#pragma unroll
                for (int q = 0; q < 3; q++) {
                    const int c = 16 * q + cl;
                    if (c < 40) B1[(size_t)row * 40 + c] = f2bf(acc[q][g] * dr);
                }
            }
        }
    }
    gsync(bar, 4);

    // ================= P6: gather40 + log-softmax -> out =================
    {
        const uint* XW32 = reinterpret_cast<const uint*>(B1);  // row stride 20 uints
        const int g = lane < 20 ? 0 : (lane < 40 ? 1 : 2);
        const int ll = lane - g * 20;
        const int llc = min(ll, 19);
        for (int node = bb * 8 + wid; node < N_NODES; node += NBLK * 8) {
            const int n = cnt[node];
            const float di = rsqrtf((float)(n + 1));
            const ushort* bkt = colb + (size_t)node * BUCKET;
            float a0 = 0.f, a1 = 0.f, b0 = 0.f, b1v = 0.f;
            int e = g;
            for (; e + 3 < n; e += 6) {
                const ushort s0 = bkt[e], s1 = bkt[e + 3];
                const uint p0 = XW32[(size_t)s0 * 20 + llc];
                const uint p1 = XW32[(size_t)s1 * 20 + llc];
                a0 += bflo(p0); a1 += bfhi(p0);
                b0 += bflo(p1); b1v += bfhi(p1);
            }
            for (; e < n; e += 3) {
                const ushort s = bkt[e];
                const uint p = XW32[(size_t)s * 20 + llc];
                a0 += bflo(p); a1 += bfhi(p);
            }
            a0 += b0; a1 += b1v;
            const float t1 = __shfl(a0, lane + 20), t2 = __shfl(a0, lane + 40);
            const float u1 = __shfl(a1, lane + 20), u2 = __shfl(a1, lane + 40);
            float v0 = -INFINITY, v1 = -INFINITY;
            if (lane < 20) {
                const uint ps = XW32[(size_t)node * 20 + lane];
                v0 = fmaf(di, (a0 + t1 + t2) + bflo(ps), b3[2 * lane]);
                v1 = fmaf(di, (a1 + u1 + u2) + bfhi(ps), b3[2 * lane + 1]);
            }
            float m = fmaxf(v0, v1);
#pragma unroll
            for (int o = 32; o > 0; o >>= 1) m = fmaxf(m, __shfl_xor(m, o));
            float s = (lane < 20) ? (expf(v0 - m) + expf(v1 - m)) : 0.f;
#pragma unroll
            for (int o = 32; o > 0; o >>= 1) s += __shfl_xor(s, o);
            if (lane < 20) {
                const float ls = m + logf(s);
                float2 r; r.x = v0 - ls; r.y = v1 - ls;
                reinterpret_cast<float2*>(out)[(size_t)node * 20 + lane] = r;
            }
        }
    }
}

extern "C" void kernel_launch(void* const* d_in, const int* in_sizes, int n_in,
                              void* d_out, int out_size, void* d_ws, size_t ws_size,
                              hipStream_t stream) {
    const float* x  = (const float*)d_in[0];
    const float* W1 = (const float*)d_in[1];
    const float* b1 = (const float*)d_in[2];
    const float* W2 = (const float*)d_in[3];
    const float* b2 = (const float*)d_in[4];
    const float* W3 = (const float*)d_in[5];
    const float* b3 = (const float*)d_in[6];
    const int* ei   = (const int*)d_in[7];
    const int* srcp = ei;
    const int* dstp = ei + N_EDGES;
    float* out = (float*)d_out;

    // ws: bar[2432 int] cnt[50176 int] colb[50000*64 ushort] B0[N*128 bf16] B1[N*128 bf16]
    int*    bar  = (int*)d_ws;
    int*    cnt  = bar + 2432;
    ushort* colb = (ushort*)(cnt + 50176);
    ushort* B0   = colb + (size_t)N_NODES * BUCKET;
    ushort* B1   = B0 + (size_t)N_NODES * 128;

    // zero barrier state + cnt in one async memset, then single persistent kernel
    hipMemsetAsync(d_ws, 0, (2432 + 50176) * sizeof(int), stream);
    gcn_persistent_k<<<NBLK, 512, 0, stream>>>(
        x, W1, b1, W2, b2, W3, b3, srcp, dstp, bar, cnt, colb, B0, B1, out);
}

// Round 13
// 254.216 us; speedup vs baseline: 2.6421x; 2.6421x over previous
//
#include <hip/hip_runtime.h>
#include <math.h>

#define N_NODES 50000
#define N_EDGES 800000
#define BUCKET 64
#define SCAT_BLKS 392   // 8 dst-range groups x 49 chunk groups
#define QPG 4082        // int4-quads per chunk group (49*4082 >= 200000)
#define GEMM_BLKS 196   // ceil(3125 row-tiles / 16)
// F_IN = HID = 128, C = 40

typedef __attribute__((ext_vector_type(8))) short short8;
typedef __attribute__((ext_vector_type(4))) float f32x4;

__device__ __forceinline__ ushort f2bf(float f) {
    union { float f; uint u; } v; v.f = f;
    uint r = v.u + 0x7FFFu + ((v.u >> 16) & 1u);  // RNE
    return (ushort)(r >> 16);
}
__device__ __forceinline__ float bflo(uint p) {
    union { uint u; float f; } v; v.u = p << 16; return v.f;
}
__device__ __forceinline__ float bfhi(uint p) {
    union { uint u; float f; } v; v.u = p & 0xFFFF0000u; return v.f;
}

// ---------------- fused: range-partitioned scatter + gemm1 (MFMA, fp32->bf16 inline) ----------------
__global__ __launch_bounds__(512) void fused_gemm1_scatter_k(
        const float* __restrict__ Af, const float* __restrict__ W, ushort* __restrict__ Y,
        const int* __restrict__ src, const int* __restrict__ dst,
        int* __restrict__ cnt, ushort* __restrict__ colb) {
    constexpr int NT = 8;
    __shared__ ushort sB[4 * NT * 64 * 8];
    const int tid = threadIdx.x;

    if (blockIdx.x < SCAT_BLKS) {
        const int r = blockIdx.x & 7;
        const int g = blockIdx.x >> 3;
        const int lo = r * 6250;
        const int4* s32 = reinterpret_cast<const int4*>(src);
        const int4* d32 = reinterpret_cast<const int4*>(dst);
        const int qbeg = g * QPG + tid;
        const int qend = min((g + 1) * QPG, N_EDGES / 4);
#pragma unroll
        for (int u = 0; u < 8; u++) {
            const int q = qbeg + u * 512;
            if (q < qend) {
                const int4 d4 = d32[q];
                const int4 s4 = s32[q];
                if ((uint)(d4.x - lo) < 6250u) {
                    int p = atomicAdd(&cnt[d4.x], 1);
                    colb[(size_t)d4.x * BUCKET + p] = (ushort)s4.x;
                }
                if ((uint)(d4.y - lo) < 6250u) {
                    int p = atomicAdd(&cnt[d4.y], 1);
                    colb[(size_t)d4.y * BUCKET + p] = (ushort)s4.y;
                }
                if ((uint)(d4.z - lo) < 6250u) {
                    int p = atomicAdd(&cnt[d4.z], 1);
                    colb[(size_t)d4.z * BUCKET + p] = (ushort)s4.z;
                }
                if ((uint)(d4.w - lo) < 6250u) {
                    int p = atomicAdd(&cnt[d4.w], 1);
                    colb[(size_t)d4.w * BUCKET + p] = (ushort)s4.w;
                }
            }
        }
        return;
    }

    // ---- gemm role: Y = cvt(x) @ W1, raw ----
    constexpr int FP = NT * 16;
    for (int i = tid; i < 128 * FP; i += 512) {
        const int k = i / FP, n = i % FP;
        const int s = k >> 5, r2 = (k >> 3) & 3, j = k & 7;
        const int t = n >> 4, nl = n & 15;
        const int l = r2 * 16 + nl;
        const int lp = (l & 56) | ((l + (l >> 3)) & 7);
        sB[(((s * NT + t) * 64) + lp) * 8 + j] = f2bf(W[k * 128 + n]);
    }
    __syncthreads();

    const int wid = tid >> 6, lane = tid & 63;
    const int lp = (lane & 56) | ((lane + (lane >> 3)) & 7);
    const int t0 = (blockIdx.x - SCAT_BLKS) * 16 + wid * 2;
    const int t1 = t0 + 1;
    const int t0c = min(t0, N_NODES / 16 - 1);
    const int t1c = min(t1, N_NODES / 16 - 1);

    f32x4 acc[2][NT];
#pragma unroll
    for (int u = 0; u < 2; u++)
#pragma unroll
        for (int t = 0; t < NT; t++) acc[u][t] = (f32x4){0.f, 0.f, 0.f, 0.f};

#pragma unroll
    for (int s = 0; s < 4; s++) {
        short8 a0, a1;
        const int ko = 32 * s + 8 * (lane >> 4);
        const float4* p0 = reinterpret_cast<const float4*>(Af + (size_t)(t0c * 16 + (lane & 15)) * 128 + ko);
        const float4* p1 = reinterpret_cast<const float4*>(Af + (size_t)(t1c * 16 + (lane & 15)) * 128 + ko);
        float4 u0 = p0[0], u1 = p0[1], v0 = p1[0], v1 = p1[1];
        a0[0] = f2bf(u0.x); a0[1] = f2bf(u0.y); a0[2] = f2bf(u0.z); a0[3] = f2bf(u0.w);
        a0[4] = f2bf(u1.x); a0[5] = f2bf(u1.y); a0[6] = f2bf(u1.z); a0[7] = f2bf(u1.w);
        a1[0] = f2bf(v0.x); a1[1] = f2bf(v0.y); a1[2] = f2bf(v0.z); a1[3] = f2bf(v0.w);
        a1[4] = f2bf(v1.x); a1[5] = f2bf(v1.y); a1[6] = f2bf(v1.z); a1[7] = f2bf(v1.w);
#pragma unroll
        for (int t = 0; t < NT; t++) {
            short8 b = *reinterpret_cast<const short8*>(&sB[(((s * NT + t) * 64) + lp) * 8]);
            acc[0][t] = __builtin_amdgcn_mfma_f32_16x16x32_bf16(a0, b, acc[0][t], 0, 0, 0);
            acc[1][t] = __builtin_amdgcn_mfma_f32_16x16x32_bf16(a1, b, acc[1][t], 0, 0, 0);
        }
    }

    const int rl = 4 * (lane >> 4), cl = lane & 15;
#pragma unroll
    for (int u = 0; u < 2; u++) {
        const int tile = u ? t1 : t0;
        if (tile >= N_NODES / 16) continue;
        const int row0 = tile * 16;
#pragma unroll
        for (int t = 0; t < NT; t++) {
            const int c = 16 * t + cl;
#pragma unroll
            for (int g = 0; g < 4; g++)
                Y[(size_t)(row0 + rl + g) * 128 + c] = f2bf(acc[u][t][g]);
        }
    }
}

// ---------------- MFMA GEMM (layers 2,3) with dinv-scaled epilogue ----------------
template <int NT>
__global__ __launch_bounds__(512) void gemm_scaled_k(const ushort* __restrict__ Ab,
                                                     const float* __restrict__ W,
                                                     const int* __restrict__ cnt,
                                                     ushort* __restrict__ Y,
                                                     const int fout) {
    __shared__ ushort sB[4 * NT * 64 * 8];
    const int tid = threadIdx.x;
    constexpr int FP = NT * 16;
    for (int i = tid; i < 128 * FP; i += 512) {
        const int k = i / FP, n = i % FP;
        const int s = k >> 5, r2 = (k >> 3) & 3, j = k & 7;
        const int t = n >> 4, nl = n & 15;
        const int l = r2 * 16 + nl;
        const int lp = (l & 56) | ((l + (l >> 3)) & 7);
        sB[(((s * NT + t) * 64) + lp) * 8 + j] = (n < fout) ? f2bf(W[k * fout + n]) : (ushort)0;
    }
    __syncthreads();

    const int wid = tid >> 6, lane = tid & 63;
    const int lp = (lane & 56) | ((lane + (lane >> 3)) & 7);
    const int t0 = blockIdx.x * 16 + wid * 2;
    const int t1 = t0 + 1;
    const int t0c = min(t0, N_NODES / 16 - 1);
    const int t1c = min(t1, N_NODES / 16 - 1);

    f32x4 acc[2][NT];
#pragma unroll
    for (int u = 0; u < 2; u++)
#pragma unroll
        for (int t = 0; t < NT; t++) acc[u][t] = (f32x4){0.f, 0.f, 0.f, 0.f};

#pragma unroll
    for (int s = 0; s < 4; s++) {
        const int ko = 32 * s + 8 * (lane >> 4);
        short8 a0 = *reinterpret_cast<const short8*>(Ab + (size_t)(t0c * 16 + (lane & 15)) * 128 + ko);
        short8 a1 = *reinterpret_cast<const short8*>(Ab + (size_t)(t1c * 16 + (lane & 15)) * 128 + ko);
#pragma unroll
        for (int t = 0; t < NT; t++) {
            short8 b = *reinterpret_cast<const short8*>(&sB[(((s * NT + t) * 64) + lp) * 8]);
            acc[0][t] = __builtin_amdgcn_mfma_f32_16x16x32_bf16(a0, b, acc[0][t], 0, 0, 0);
            acc[1][t] = __builtin_amdgcn_mfma_f32_16x16x32_bf16(a1, b, acc[1][t], 0, 0, 0);
        }
    }

    const int rl = 4 * (lane >> 4), cl = lane & 15;
#pragma unroll
    for (int u = 0; u < 2; u++) {
        const int tile = u ? t1 : t0;
        if (tile >= N_NODES / 16) continue;
        const int row0 = tile * 16;
#pragma unroll
        for (int g = 0; g < 4; g++) {
            const int row = row0 + rl + g;
            const float dr = rsqrtf((float)(cnt[row] + 1));
#pragma unroll
            for (int t = 0; t < NT; t++) {
                const int c = 16 * t + cl;
                if (NT == 3 && c >= fout) continue;
                Y[(size_t)row * fout + c] = f2bf(acc[u][t][g] * dr);
            }
        }
    }
}

// ---------------- layer-1 gather: weighted, 8 row-loads in flight ----------------
__global__ __launch_bounds__(256) void gather1_k(const ushort* __restrict__ XW,
                                                 const int* __restrict__ cnt,
                                                 const ushort* __restrict__ colb,
                                                 const float* __restrict__ bias,
                                                 ushort* __restrict__ out) {
    const int node = (blockIdx.x * 256 + threadIdx.x) >> 6;
    const int lane = threadIdx.x & 63;
    if (node >= N_NODES) return;
    const int n = cnt[node];
    const float di = rsqrtf((float)(n + 1));
    int sl = 0; float wl = 0.f;
    if (lane < n) {
        sl = colb[(size_t)node * BUCKET + lane];
        wl = rsqrtf((float)(cnt[sl] + 1));
    }
    const uint* XW32 = reinterpret_cast<const uint*>(XW);  // row stride 64 uints

    float x0 = 0.f, x1 = 0.f, y0 = 0.f, y1 = 0.f;
    int e = 0;
    for (; e + 8 <= n; e += 8) {
        int s[8]; float w[8]; uint p[8];
#pragma unroll
        for (int i = 0; i < 8; i++) { s[i] = __shfl(sl, e + i); w[i] = __shfl(wl, e + i); }
#pragma unroll
        for (int i = 0; i < 8; i++) p[i] = XW32[(size_t)s[i] * 64 + lane];
#pragma unroll
        for (int i = 0; i < 8; i++) {
            if (i & 1) { y0 = fmaf(bflo(p[i]), w[i], y0); y1 = fmaf(bfhi(p[i]), w[i], y1); }
            else       { x0 = fmaf(bflo(p[i]), w[i], x0); x1 = fmaf(bfhi(p[i]), w[i], x1); }
        }
    }
    for (; e < n; e++) {
        const int s = __shfl(sl, e);
        const float w = __shfl(wl, e);
        const uint p = XW32[(size_t)s * 64 + lane];
        x0 = fmaf(bflo(p), w, x0); x1 = fmaf(bfhi(p), w, x1);
    }
    const uint ps = XW32[(size_t)node * 64 + lane];
    float t0 = x0 + y0; t0 = fmaf(bflo(ps), di, t0);
    float t1 = x1 + y1; t1 = fmaf(bfhi(ps), di, t1);
    const float o0 = fmaxf(fmaf(di, t0, bias[2 * lane]), 0.f);
    const float o1 = fmaxf(fmaf(di, t1, bias[2 * lane + 1]), 0.f);
    reinterpret_cast<uint*>(out)[(size_t)node * 64 + lane] =
        (uint)f2bf(o0) | ((uint)f2bf(o1) << 16);
}

// ---------------- layer-2 gather: pure add (rows pre-scaled), 8 row-loads in flight ----------------
__global__ __launch_bounds__(256) void gather_add_k(const ushort* __restrict__ XWn,
                                                    const int* __restrict__ cnt,
                                                    const ushort* __restrict__ colb,
                                                    const float* __restrict__ bias,
                                                    ushort* __restrict__ out) {
    const int node = (blockIdx.x * 256 + threadIdx.x) >> 6;
    const int lane = threadIdx.x & 63;
    if (node >= N_NODES) return;
    const int n = cnt[node];
    const float di = rsqrtf((float)(n + 1));
    const ushort4* bucket = reinterpret_cast<const ushort4*>(colb + (size_t)node * BUCKET);
    const uint* XW32 = reinterpret_cast<const uint*>(XWn);  // row stride 64 uints

    float x0 = 0.f, x1 = 0.f, y0 = 0.f, y1 = 0.f;
    int e = 0;
    for (; e + 8 <= n; e += 8) {
        const ushort4 sa = bucket[e >> 2], sb = bucket[(e >> 2) + 1];
        uint p[8];
        p[0] = XW32[(size_t)sa.x * 64 + lane];
        p[1] = XW32[(size_t)sa.y * 64 + lane];
        p[2] = XW32[(size_t)sa.z * 64 + lane];
        p[3] = XW32[(size_t)sa.w * 64 + lane];
        p[4] = XW32[(size_t)sb.x * 64 + lane];
        p[5] = XW32[(size_t)sb.y * 64 + lane];
        p[6] = XW32[(size_t)sb.z * 64 + lane];
        p[7] = XW32[(size_t)sb.w * 64 + lane];
#pragma unroll
        for (int i = 0; i < 8; i++) {
            if (i & 1) { y0 += bflo(p[i]); y1 += bfhi(p[i]); }
            else       { x0 += bflo(p[i]); x1 += bfhi(p[i]); }
        }
    }
    for (; e < n; e++) {
        const ushort s = colb[(size_t)node * BUCKET + e];
        const uint p = XW32[(size_t)s * 64 + lane];
        x0 += bflo(p); x1 += bfhi(p);
    }
    const uint ps = XW32[(size_t)node * 64 + lane];
    const float t0 = (x0 + y0) + bflo(ps);
    const float t1 = (x1 + y1) + bfhi(ps);
    const float o0 = fmaxf(fmaf(di, t0, bias[2 * lane]), 0.f);
    const float o1 = fmaxf(fmaf(di, t1, bias[2 * lane + 1]), 0.f);
    reinterpret_cast<uint*>(out)[(size_t)node * 64 + lane] =
        (uint)f2bf(o0) | ((uint)f2bf(o1) << 16);
}

// ---------------- layer 3: pure-add gather (F=40, pre-scaled) + log-softmax, 4x per group ----------------
__global__ __launch_bounds__(256) void gather40_lsm_k(const ushort* __restrict__ XWn,
                                                      const int* __restrict__ cnt,
                                                      const ushort* __restrict__ colb,
                                                      const float* __restrict__ bias,
                                                      float* __restrict__ out) {
    const int node = (blockIdx.x * 256 + threadIdx.x) >> 6;
    const int lane = threadIdx.x & 63;
    if (node >= N_NODES) return;
    const int g = lane < 20 ? 0 : (lane < 40 ? 1 : 2);
    const int ll = lane - g * 20;
    const int llc = min(ll, 19);
    const int n = cnt[node];
    const float di = rsqrtf((float)(n + 1));
    const uint* XW32 = reinterpret_cast<const uint*>(XWn);  // row stride 20 uints
    const ushort* bkt = colb + (size_t)node * BUCKET;

    float a0 = 0.f, a1 = 0.f, b0 = 0.f, b1 = 0.f;
    float c0 = 0.f, c1 = 0.f, d0 = 0.f, d1 = 0.f;
    int e = g;
    for (; e + 9 < n; e += 12) {                 // 12 edges in flight per wave (4/group)
        const ushort s0 = bkt[e], s1 = bkt[e + 3], s2 = bkt[e + 6], s3 = bkt[e + 9];
        const uint p0 = XW32[(size_t)s0 * 20 + llc];
        const uint p1 = XW32[(size_t)s1 * 20 + llc];
        const uint p2 = XW32[(size_t)s2 * 20 + llc];
        const uint p3 = XW32[(size_t)s3 * 20 + llc];
        a0 += bflo(p0); a1 += bfhi(p0);
        b0 += bflo(p1); b1 += bfhi(p1);
        c0 += bflo(p2); c1 += bfhi(p2);
        d0 += bflo(p3); d1 += bfhi(p3);
    }
    for (; e < n; e += 3) {
        const ushort s = bkt[e];
        const uint p = XW32[(size_t)s * 20 + llc];
        a0 += bflo(p); a1 += bfhi(p);
    }
    a0 = (a0 + b0) + (c0 + d0);
    a1 = (a1 + b1) + (c1 + d1);
    const float t1 = __shfl(a0, lane + 20), t2 = __shfl(a0, lane + 40);
    const float u1 = __shfl(a1, lane + 20), u2 = __shfl(a1, lane + 40);
    float v0 = -INFINITY, v1 = -INFINITY;
    if (lane < 20) {
        const uint ps = XW32[(size_t)node * 20 + lane];
        v0 = fmaf(di, (a0 + t1 + t2) + bflo(ps), bias[2 * lane]);
        v1 = fmaf(di, (a1 + u1 + u2) + bfhi(ps), bias[2 * lane + 1]);
    }
    float m = fmaxf(v0, v1);
#pragma unroll
    for (int o = 32; o > 0; o >>= 1) m = fmaxf(m, __shfl_xor(m, o));
    float s = (lane < 20) ? (expf(v0 - m) + expf(v1 - m)) : 0.f;
#pragma unroll
    for (int o = 32; o > 0; o >>= 1) s += __shfl_xor(s, o);
    if (lane < 20) {
        const float ls = m + logf(s);
        float2 r; r.x = v0 - ls; r.y = v1 - ls;
        reinterpret_cast<float2*>(out)[(size_t)node * 20 + lane] = r;
    }
}

extern "C" void kernel_launch(void* const* d_in, const int* in_sizes, int n_in,
                              void* d_out, int out_size, void* d_ws, size_t ws_size,
                              hipStream_t stream) {
    const float* x  = (const float*)d_in[0];
    const float* W1 = (const float*)d_in[1];
    const float* b1 = (const float*)d_in[2];
    const float* W2 = (const float*)d_in[3];
    const float* b2 = (const float*)d_in[4];
    const float* W3 = (const float*)d_in[5];
    const float* b3 = (const float*)d_in[6];
    const int* ei   = (const int*)d_in[7];
    const int* srcp = ei;
    const int* dstp = ei + N_EDGES;
    float* out = (float*)d_out;

    // workspace: cnt[50176 int] colb[50000*64 ushort] B0[N*128 bf16] B1[N*128 bf16]
    int*    cnt  = (int*)d_ws;
    ushort* colb = (ushort*)(cnt + 50176);
    ushort* B0   = colb + (size_t)N_NODES * BUCKET;   // 16B aligned
    ushort* B1   = B0 + (size_t)N_NODES * 128;

    const int NB_W = (N_NODES * 64) / 256;   // 12500 (one wave per node)

    hipMemsetAsync(cnt, 0, 50176 * sizeof(int), stream);
    // range-partitioned scatter overlapped with gemm1 (XW1 = cvt(x) @ W1, raw)
    fused_gemm1_scatter_k<<<SCAT_BLKS + GEMM_BLKS, 512, 0, stream>>>(
        x, W1, B1, srcp, dstp, cnt, colb);
    // h1 = relu(Ahat @ XW1 + b1)
    gather1_k<<<NB_W, 256, 0, stream>>>(B1, cnt, colb, b1, B0);
    // XW2n = (h1 @ W2) * dinv[row]
    gemm_scaled_k<8><<<GEMM_BLKS, 512, 0, stream>>>(B0, W2, cnt, B1, 128);
    // h2 = relu(di*(sum XW2n + self) + b2)
    gather_add_k<<<NB_W, 256, 0, stream>>>(B1, cnt, colb, b2, B0);
    // XW3n = (h2 @ W3) * dinv[row]
    gemm_scaled_k<3><<<GEMM_BLKS, 512, 0, stream>>>(B0, W3, cnt, B1, 40);
    // logits + log-softmax
    gather40_lsm_k<<<NB_W, 256, 0, stream>>>(B1, cnt, colb, b3, out);
}